// Round 6
// baseline (39.072 us; speedup 1.0000x reference)
//
#include <hip/hip_runtime.h>
#include <math.h>

// Problem constants (from the reference file)
constexpr int B_   = 128;
constexpr int S_   = 2048;
constexpr int EMB_ = 128;
constexpr int HID_ = 256;
constexpr int OUT_ = 32;

constexpr int HT   = 8;         // h per block (round-3 proven geometry)
constexpr int BH   = 64;        // b per block (half the batch)
constexpr int PADK = EMB_ + 4;  // 132: 16B-aligned rows, stride%32==4 -> conflict-free b128
constexpr int NBLK = 128;       // 2 dirs x 32 h-tiles x 2 b-halves

// Fixed-point scale for deterministic integer atomics (order-independent sum).
constexpr float QS  = 16777216.0f;        // 2^24
constexpr float QSI = 1.0f / 16777216.0f;

// ws layout:
//   [0, 32KB)  : lgQ u64[B][OUT] fixed-point logit accumulators
//   [32768]    : u32 arrival counter
// both zeroed by ONE hipMemsetAsync each call.
constexpr size_t CTR_OFF = (size_t)B_ * OUT_ * 8;   // 32768

__global__ __launch_bounds__(512) void bilstm_one(
    const int*   __restrict__ inputs,
    const float* __restrict__ weight,
    const float* __restrict__ Wxf, const float* __restrict__ bxf, const float* __restrict__ bhf,
    const float* __restrict__ Wxb, const float* __restrict__ bxb, const float* __restrict__ bhb,
    const float* __restrict__ Why, const float* __restrict__ by,
    unsigned long long* __restrict__ lgQ,   // [B][OUT]
    unsigned int*       __restrict__ ctr,
    float*              __restrict__ out)
{
    __shared__ __align__(16) float Xs[BH][PADK];      // 33.8 KB (tail reuses as lg[4096])
    __shared__ __align__(16) float Ws[3][HT][PADK];   // 12.7 KB (tail reuses as m_s/s_s)
    __shared__ float Whys[OUT_][9];                   // 1.2 KB (stride 9: conflict-free)
    __shared__ float hy_s[BH][HT];                    // 2 KB
    __shared__ int   toks[BH];
    __shared__ int   is_last;

    const int blk   = blockIdx.x;
    const int dir   = blk >> 6;          // 64 blocks per direction
    const int ht    = (blk & 63) >> 1;   // 0..31
    const int bhalf = blk & 1;
    const int h0    = ht * HT;
    const int tid   = threadIdx.x;

    if (tid < BH)
        toks[tid] = inputs[(size_t)(bhalf * BH + tid) * S_ + (dir ? 0 : (S_ - 1))];
    __syncthreads();

    // ---- stage X: 64 rows x 32 float4, 4 passes of 512
    #pragma unroll
    for (int p = 0; p < 4; ++p) {
        const int idx = p * 512 + tid;
        const int bl  = idx >> 5;
        const int j   = idx & 31;
        const float4 v = reinterpret_cast<const float4*>(weight + (size_t)toks[bl] * EMB_)[j];
        *reinterpret_cast<float4*>(&Xs[bl][4 * j]) = v;
    }
    // ---- stage W: 3 gates x 8 rows x 32 float4
    {
        const float* Wx = dir ? Wxb : Wxf;
        for (int idx = tid; idx < 3 * HT * 32; idx += 512) {
            const int g   = idx >> 8;
            const int rem = idx & 255;
            const int hl  = rem >> 5;
            const int j   = rem & 31;
            const int grow = (g == 0) ? 0 : ((g == 1) ? 2 : 3);  // i, g, o rows
            const float4 v = reinterpret_cast<const float4*>(
                Wx + (size_t)(grow * HID_ + h0 + hl) * EMB_)[j];
            *reinterpret_cast<float4*>(&Ws[g][hl][4 * j]) = v;
        }
    }
    // ---- stage Why tile: [32 o][8 hl]
    if (tid < OUT_ * HT) {
        const int o  = tid >> 3;
        const int hl = tid & 7;
        Whys[o][hl] = Why[(size_t)o * HID_ + h0 + hl];
    }
    __syncthreads();

    // ---- gates: thread = (hl, bg)  [round-3 proven body]
    {
        const int hl = tid & (HT - 1);
        const int bg = tid >> 3;
        const int h  = h0 + hl;
        const float* bx = dir ? bxb : bxf;
        const float* bh = dir ? bhb : bhf;
        float gi = bx[h]            + bh[h];
        float gg = bx[2 * HID_ + h] + bh[2 * HID_ + h];
        float go = bx[3 * HID_ + h] + bh[3 * HID_ + h];

        #pragma unroll 8
        for (int k4 = 0; k4 < EMB_ / 4; ++k4) {
            const float4 x  = *reinterpret_cast<const float4*>(&Xs[bg][4 * k4]);
            const float4 wi = *reinterpret_cast<const float4*>(&Ws[0][hl][4 * k4]);
            const float4 wg = *reinterpret_cast<const float4*>(&Ws[1][hl][4 * k4]);
            const float4 wo = *reinterpret_cast<const float4*>(&Ws[2][hl][4 * k4]);
            gi = fmaf(x.x, wi.x, fmaf(x.y, wi.y, fmaf(x.z, wi.z, fmaf(x.w, wi.w, gi))));
            gg = fmaf(x.x, wg.x, fmaf(x.y, wg.y, fmaf(x.z, wg.z, fmaf(x.w, wg.w, gg))));
            go = fmaf(x.x, wo.x, fmaf(x.y, wo.y, fmaf(x.z, wo.z, fmaf(x.w, wo.w, go))));
        }
        const float si = 1.0f / (1.0f + expf(-gi));
        const float so = 1.0f / (1.0f + expf(-go));
        hy_s[bg][hl] = so * tanhf(si * tanhf(gg));
    }
    __syncthreads();

    // ---- partial logits -> deterministic fixed-point atomic accumulate
    #pragma unroll
    for (int i = 0; i < 4; ++i) {
        const int p  = tid + 512 * i;      // 0..2047
        const int bl = p >> 5;             // 0..63
        const int o  = p & 31;
        float acc = 0.0f;
        #pragma unroll
        for (int hl = 0; hl < HT; ++hl)
            acc = fmaf(hy_s[bl][hl], Whys[o][hl], acc);
        const long long q = llrintf(acc * QS);
        atomicAdd(&lgQ[(size_t)(bhalf * BH + bl) * OUT_ + o], (unsigned long long)q);
    }

    // ---- arrival: release + exact counter; 128th arriver runs the tail
    __threadfence();
    __syncthreads();
    if (tid == 0) {
        const unsigned int old = atomicAdd(ctr, 1u);
        is_last = (old == NBLK - 1) ? 1 : 0;
        __threadfence();
    }
    __syncthreads();
    if (!is_last) return;

    // ---- tail: decode 32 KB of accumulators, add by, log-softmax
    float* lg  = &Xs[0][0];                 // reuse LDS (4096 floats)
    float* m_s = &Ws[0][0][0];
    float* s_s = m_s + B_;
    #pragma unroll
    for (int i = 0; i < 8; ++i) {
        const int q = tid + 512 * i;        // 0..4095
        const int o = q & 31;
        // atomic read: guaranteed coherent view of other XCDs' accumulations
        const unsigned long long v = atomicAdd(&lgQ[q], 0ull);
        lg[q] = (float)(long long)v * QSI + by[o];
    }
    __syncthreads();
    if (tid < B_) {
        float m = -1e30f;
        #pragma unroll 8
        for (int o = 0; o < OUT_; ++o) m = fmaxf(m, lg[tid * OUT_ + o]);
        float s = 0.0f;
        #pragma unroll 8
        for (int o = 0; o < OUT_; ++o) s += expf(lg[tid * OUT_ + o] - m);
        m_s[tid] = m;
        s_s[tid] = logf(s);
    }
    __syncthreads();
    #pragma unroll
    for (int i = 0; i < 8; ++i) {
        const int q = tid + 512 * i;
        const int b = q >> 5;
        out[q] = lg[q] - m_s[b] - s_s[b];
    }
}

extern "C" void kernel_launch(void* const* d_in, const int* in_sizes, int n_in,
                              void* d_out, int out_size, void* d_ws, size_t ws_size,
                              hipStream_t stream) {
    // setup_inputs() order:
    // 0 inputs [B,S] int32      1 weight [VOCAB,EMB] f32
    // 2 Wxf [1024,128]  3 bxf [1024]  4 Whf (dead)  5 bhf [1024]
    // 6 Wxb [1024,128]  7 bxb [1024]  8 Whb (dead)  9 bhb [1024]
    // 10 Why [32,256]   11 by [32]
    const int*   inputs = (const int*)  d_in[0];
    const float* weight = (const float*)d_in[1];
    const float* Wxf    = (const float*)d_in[2];
    const float* bxf    = (const float*)d_in[3];
    const float* bhf    = (const float*)d_in[5];
    const float* Wxb    = (const float*)d_in[6];
    const float* bxb    = (const float*)d_in[7];
    const float* bhb    = (const float*)d_in[9];
    const float* Why    = (const float*)d_in[10];
    const float* by     = (const float*)d_in[11];
    float* out = (float*)d_out;

    unsigned long long* lgQ = (unsigned long long*)d_ws;
    unsigned int*       ctr = (unsigned int*)((char*)d_ws + CTR_OFF);

    // Zero accumulators + counter in one small async memset (graph-legal).
    hipMemsetAsync(d_ws, 0, CTR_OFF + sizeof(unsigned int), stream);

    bilstm_one<<<NBLK, 512, 0, stream>>>(inputs, weight,
                                         Wxf, bxf, bhf,
                                         Wxb, bxb, bhb,
                                         Why, by, lgQ, ctr, out);
}